// Round 1
// baseline (3552.133 us; speedup 1.0000x reference)
//
#include <hip/hip_runtime.h>
#include <cstdint>

#define Bc 256
#define Cc 64
#define Hc 128
#define Oc 64
#define Tc 512

// ---------------------------------------------------------------------------
// K1: x_last select-scan. One thread per (b,c), walks t. Reads contiguous in t
// per thread (lines L1-cached across iterations), writes coalesced across c.
// ---------------------------------------------------------------------------
__global__ __launch_bounds__(256) void k_scan(const float* __restrict__ input,
                                              const float* __restrict__ lastx,
                                              float* __restrict__ xlast) {
  int gid = blockIdx.x * blockDim.x + threadIdx.x;   // 0 .. B*C-1
  int b = gid >> 6, c = gid & 63;
  const float* xp = input + ((size_t)(b * 3 + 0) * Cc + c) * Tc;
  const float* mp = input + ((size_t)(b * 3 + 1) * Cc + c) * Tc;
  float xl = lastx[b * Cc + c];
  float* outp = xlast + (size_t)b * Tc * Cc + c;
  for (int t = 0; t < Tc; t += 4) {
    const float4 x4 = *reinterpret_cast<const float4*>(xp + t);
    const float4 m4 = *reinterpret_cast<const float4*>(mp + t);
    xl = (m4.x > 0.f) ? x4.x : xl; outp[(size_t)(t + 0) * Cc] = xl;
    xl = (m4.y > 0.f) ? x4.y : xl; outp[(size_t)(t + 1) * Cc] = xl;
    xl = (m4.z > 0.f) ? x4.z : xl; outp[(size_t)(t + 2) * Cc] = xl;
    xl = (m4.w > 0.f) ? x4.w : xl; outp[(size_t)(t + 3) * Cc] = xl;
  }
}

// ---------------------------------------------------------------------------
// K2: fused gamma_x/gamma_h + xin + input-side pre-GEMM.
// Block = 256 threads handles 32 (b,t) rows (same b).
//   Phase A: gamma = exp(-relu(d @ [w_dg_x|w_dg_h] + b)), xin into LDS,
//            gamma_h to global. 2 column passes of 96 to keep LDS <= 56KB.
//   Phase B: pre_{z,r,h} = [xin|m] @ [[w_x*],[w_m*]] (+bias), 6 chunks of 64.
// ---------------------------------------------------------------------------
__global__ __launch_bounds__(256) void k_pre(
    const float* __restrict__ input, const float* __restrict__ x_mean,
    const float* __restrict__ xlast,
    const float* __restrict__ w_dg_x, const float* __restrict__ b_dg_x,
    const float* __restrict__ w_dg_h, const float* __restrict__ b_dg_h,
    const float* __restrict__ w_xz, const float* __restrict__ w_mz, const float* __restrict__ b_mz,
    const float* __restrict__ w_xr, const float* __restrict__ w_mr,
    const float* __restrict__ w_xh, const float* __restrict__ w_mh, const float* __restrict__ b_mh,
    float* __restrict__ gamma_h, float* __restrict__ pre_z,
    float* __restrict__ pre_r, float* __restrict__ pre_h) {
  __shared__ float d_s[32][Cc];     // 8 KB
  __shared__ float m_s[32][Cc];     // 8 KB
  __shared__ float xin_s[32][Cc];   // 8 KB
  __shared__ float wbuf[8192];      // 32 KB, reused: wdg half (64x96) / pre chunk (128x64)
  const int tid = threadIdx.x;
  const int row0 = blockIdx.x * 32;
  const int b = row0 >> 9;          // / T
  const int t0 = row0 & 511;        // % T

  // stage D and M tiles (contiguous 32-float runs in t per c)
  #pragma unroll
  for (int i = 0; i < 8; ++i) {
    int e = tid + i * 256;
    int c = e >> 5, tt = e & 31;
    d_s[tt][c] = input[((size_t)(b * 3 + 2) * Cc + c) * Tc + t0 + tt];
    m_s[tt][c] = input[((size_t)(b * 3 + 1) * Cc + c) * Tc + t0 + tt];
  }

  // -------- Phase A: gamma + xin (2 passes over 192 columns) --------
  for (int p = 0; p < 2; ++p) {
    #pragma unroll
    for (int i = 0; i < 24; ++i) {
      int e = tid + i * 256;                 // 0..6143
      int k = e / 96, lcol = e % 96;
      int col = p * 96 + lcol;
      wbuf[k * 96 + lcol] = (col < 64) ? w_dg_x[k * Cc + col]
                                       : w_dg_h[k * Hc + (col - 64)];
    }
    __syncthreads();
    #pragma unroll
    for (int i = 0; i < 12; ++i) {
      int e = tid + i * 256;                 // 0..3071
      int row = e / 96, lcol = e % 96;
      int col = p * 96 + lcol;
      float acc = (col < 64) ? b_dg_x[col] : b_dg_h[col - 64];
      #pragma unroll 8
      for (int k = 0; k < 64; ++k) acc += d_s[row][k] * wbuf[k * 96 + lcol];
      float g = __expf(-fmaxf(acc, 0.f));
      if (col < 64) {
        float mv  = m_s[row][col];
        float xv  = input[((size_t)(b * 3 + 0) * Cc + col) * Tc + t0 + row];
        float xlv = xlast[((size_t)(b * Tc + t0 + row)) * Cc + col];
        float xmn = x_mean[b * Cc + col];
        xin_s[row][col] = mv * xv + (1.f - mv) * (g * xlv + (1.f - g) * xmn);
      } else {
        gamma_h[((size_t)(b * Tc + t0 + row)) * Hc + (col - 64)] = g;
      }
    }
    __syncthreads();
  }

  // -------- Phase B: pre_{z,r,h} GEMM, K=128 ([xin|m]), 6 N-chunks of 64 ----
  const float* wxs[3] = {w_xz, w_xr, w_xh};
  const float* wms[3] = {w_mz, w_mr, w_mh};
  float* outs[3] = {pre_z, pre_r, pre_h};
  for (int cc = 0; cc < 6; ++cc) {
    int bufi = cc >> 1, half = cc & 1;
    const float* wxp = wxs[bufi];
    const float* wmp = wms[bufi];
    #pragma unroll
    for (int i = 0; i < 32; ++i) {
      int e = tid + i * 256;                 // 0..8191
      int k = e >> 6, jj = e & 63;
      wbuf[k * 64 + jj] = (k < 64) ? wxp[(size_t)k * Hc + half * 64 + jj]
                                   : wmp[(size_t)(k - 64) * Hc + half * 64 + jj];
    }
    __syncthreads();
    int col = tid & 63, rbase = tid >> 6;
    float acc[8] = {0.f, 0.f, 0.f, 0.f, 0.f, 0.f, 0.f, 0.f};
    #pragma unroll 4
    for (int k = 0; k < 64; ++k) {
      float wv = wbuf[k * 64 + col];
      #pragma unroll
      for (int it = 0; it < 8; ++it) acc[it] += xin_s[rbase + it * 4][k] * wv;
    }
    #pragma unroll 4
    for (int k = 0; k < 64; ++k) {
      float wv = wbuf[(k + 64) * 64 + col];
      #pragma unroll
      for (int it = 0; it < 8; ++it) acc[it] += m_s[rbase + it * 4][k] * wv;
    }
    float bias = 0.f;
    if (bufi == 0) bias = b_mz[half * 64 + col];
    if (bufi == 2) bias = b_mh[half * 64 + col];
    float* op = outs[bufi];
    #pragma unroll
    for (int it = 0; it < 8; ++it) {
      int row = rbase + it * 4;
      op[((size_t)(b * Tc + t0 + row)) * Hc + half * 64 + col] = acc[it] + bias;
    }
    __syncthreads();
  }
}

// ---------------------------------------------------------------------------
// K3: the sequential h-recurrence. One block per batch row b (256 blocks =
// 1 block/CU), 384 threads: j<128 -> z column j (+ state owner of h[j]),
// 128..255 -> r column, 256..383 -> h~ column. Weight columns live in VGPRs
// (128 each); hd broadcast via LDS float4 reads. Wave-aligned role branches.
// ---------------------------------------------------------------------------
__global__ __launch_bounds__(384, 2) void k_seq(
    const float* __restrict__ gamma_h, const float* __restrict__ pre_z,
    const float* __restrict__ pre_r, const float* __restrict__ pre_h,
    const float* __restrict__ w_hz, const float* __restrict__ w_hr,
    const float* __restrict__ w_hh, float* __restrict__ hs_out) {
  const int b = blockIdx.x;
  const int j = threadIdx.x;
  __shared__ __align__(16) float hd_s[Hc];
  __shared__ __align__(16) float rhd_s[Hc];
  __shared__ __align__(16) float ht_s[Hc];

  float wcol[Hc];
  {
    const float* wsrc = (j < 128) ? (w_hz + j)
                       : (j < 256) ? (w_hr + (j - 128))
                                   : (w_hh + (j - 256));
    #pragma unroll
    for (int k = 0; k < Hc; ++k) wcol[k] = wsrc[(size_t)k * Hc];
  }

  float h_j = 0.f, z_j = 0.f, hd_j = 0.f;
  for (int t = 0; t < Tc; ++t) {
    const size_t base = ((size_t)b * Tc + t) * Hc;
    if (j < 128) {
      hd_j = gamma_h[base + j] * h_j;
      hd_s[j] = hd_j;
    }
    __syncthreads();
    if (j < 256) {
      float acc = (j < 128) ? pre_z[base + j] : pre_r[base + j - 128];
      #pragma unroll
      for (int k = 0; k < Hc; k += 4) {
        const float4 hv = *reinterpret_cast<const float4*>(&hd_s[k]);
        acc += hv.x * wcol[k] + hv.y * wcol[k + 1] + hv.z * wcol[k + 2] + hv.w * wcol[k + 3];
      }
      float g = 1.f / (1.f + __expf(-acc));
      if (j < 128) z_j = g;
      else         rhd_s[j - 128] = g * hd_s[j - 128];
    }
    __syncthreads();
    if (j >= 256) {
      float acc = pre_h[base + j - 256];
      #pragma unroll
      for (int k = 0; k < Hc; k += 4) {
        const float4 rv = *reinterpret_cast<const float4*>(&rhd_s[k]);
        acc += rv.x * wcol[k] + rv.y * wcol[k + 1] + rv.z * wcol[k + 2] + rv.w * wcol[k + 3];
      }
      ht_s[j - 256] = tanhf(acc);
    }
    __syncthreads();
    if (j < 128) {
      float hn = (1.f - z_j) * hd_j + z_j * ht_s[j];
      h_j = hn;
      hs_out[base + j] = hn;
    }
  }
}

// ---------------------------------------------------------------------------
// K4: ys = sigmoid(hs @ w_hy + b_hy). Parallel epilogue GEMM, 32 rows/block.
// ---------------------------------------------------------------------------
__global__ __launch_bounds__(256) void k_y(const float* __restrict__ hs,
                                           const float* __restrict__ w_hy,
                                           const float* __restrict__ b_hy,
                                           float* __restrict__ ys) {
  __shared__ float wy_s[Hc * Oc];   // 32 KB
  __shared__ float hh_s[32][Hc];    // 16 KB
  const int tid = threadIdx.x;
  const int row0 = blockIdx.x * 32;
  #pragma unroll
  for (int i = 0; i < 32; ++i) {
    int e = tid + i * 256;          // 0..8191
    wy_s[e] = w_hy[e];
  }
  #pragma unroll
  for (int i = 0; i < 16; ++i) {
    int e = tid + i * 256;          // 0..4095
    int r = e >> 7, k = e & 127;
    hh_s[r][k] = hs[((size_t)(row0 + r)) * Hc + k];
  }
  __syncthreads();
  int col = tid & 63, rbase = tid >> 6;
  float acc[8] = {0.f, 0.f, 0.f, 0.f, 0.f, 0.f, 0.f, 0.f};
  #pragma unroll 4
  for (int k = 0; k < Hc; ++k) {
    float wv = wy_s[k * Oc + col];
    #pragma unroll
    for (int it = 0; it < 8; ++it) acc[it] += hh_s[rbase + it * 4][k] * wv;
  }
  float bias = b_hy[col];
  #pragma unroll
  for (int it = 0; it < 8; ++it) {
    int r = rbase + it * 4;
    ys[((size_t)(row0 + r)) * Oc + col] = 1.f / (1.f + __expf(-(acc[it] + bias)));
  }
}

// ---------------------------------------------------------------------------
extern "C" void kernel_launch(void* const* d_in, const int* in_sizes, int n_in,
                              void* d_out, int out_size, void* d_ws, size_t ws_size,
                              hipStream_t stream) {
  const float* input  = (const float*)d_in[0];
  const float* x_mean = (const float*)d_in[1];
  const float* lastx  = (const float*)d_in[2];
  const float* w_dg_x = (const float*)d_in[3];
  const float* b_dg_x = (const float*)d_in[4];
  const float* w_dg_h = (const float*)d_in[5];
  const float* b_dg_h = (const float*)d_in[6];
  const float* w_xz   = (const float*)d_in[7];
  const float* w_hz   = (const float*)d_in[8];
  const float* w_mz   = (const float*)d_in[9];
  const float* b_mz   = (const float*)d_in[10];
  const float* w_xr   = (const float*)d_in[11];
  const float* w_hr   = (const float*)d_in[12];
  const float* w_mr   = (const float*)d_in[13];
  const float* w_xh   = (const float*)d_in[14];
  const float* w_hh   = (const float*)d_in[15];
  const float* w_mh   = (const float*)d_in[16];
  const float* b_mh   = (const float*)d_in[17];
  const float* w_hy   = (const float*)d_in[18];
  const float* b_hy   = (const float*)d_in[19];

  float* ys = (float*)d_out;                          // (B,T,O)
  float* hs = (float*)d_out + (size_t)Bc * Tc * Oc;   // (B,T,H)

  float* ws      = (float*)d_ws;
  float* xlast   = ws;                                      // B*T*C
  float* gamma_h = xlast + (size_t)Bc * Tc * Cc;            // B*T*H
  float* pre_z   = gamma_h + (size_t)Bc * Tc * Hc;          // B*T*H
  float* pre_r   = pre_z + (size_t)Bc * Tc * Hc;            // B*T*H
  float* pre_h   = pre_r + (size_t)Bc * Tc * Hc;            // B*T*H
  // total ws need: (B*T*C + 4*B*T*H) * 4 bytes = ~302 MB

  k_scan<<<(Bc * Cc) / 256, 256, 0, stream>>>(input, lastx, xlast);
  k_pre<<<(Bc * Tc) / 32, 256, 0, stream>>>(input, x_mean, xlast,
                                            w_dg_x, b_dg_x, w_dg_h, b_dg_h,
                                            w_xz, w_mz, b_mz, w_xr, w_mr,
                                            w_xh, w_mh, b_mh,
                                            gamma_h, pre_z, pre_r, pre_h);
  k_seq<<<Bc, 384, 0, stream>>>(gamma_h, pre_z, pre_r, pre_h,
                                w_hz, w_hr, w_hh, hs);
  k_y<<<(Bc * Tc) / 32, 256, 0, stream>>>(hs, w_hy, b_hy, ys);
}

// Round 2
// 1887.126 us; speedup vs baseline: 1.8823x; 1.8823x over previous
//
#include <hip/hip_runtime.h>
#include <cstdint>

#define Bc 256
#define Cc 64
#define Hc 128
#define Oc 64
#define Tc 512

// ---------------------------------------------------------------------------
// K1: x_last select-scan. One thread per (b,c), walks t.
// ---------------------------------------------------------------------------
__global__ __launch_bounds__(256) void k_scan(const float* __restrict__ input,
                                              const float* __restrict__ lastx,
                                              float* __restrict__ xlast) {
  int gid = blockIdx.x * blockDim.x + threadIdx.x;   // 0 .. B*C-1
  int b = gid >> 6, c = gid & 63;
  const float* xp = input + ((size_t)(b * 3 + 0) * Cc + c) * Tc;
  const float* mp = input + ((size_t)(b * 3 + 1) * Cc + c) * Tc;
  float xl = lastx[b * Cc + c];
  float* outp = xlast + (size_t)b * Tc * Cc + c;
  for (int t = 0; t < Tc; t += 4) {
    const float4 x4 = *reinterpret_cast<const float4*>(xp + t);
    const float4 m4 = *reinterpret_cast<const float4*>(mp + t);
    xl = (m4.x > 0.f) ? x4.x : xl; outp[(size_t)(t + 0) * Cc] = xl;
    xl = (m4.y > 0.f) ? x4.y : xl; outp[(size_t)(t + 1) * Cc] = xl;
    xl = (m4.z > 0.f) ? x4.z : xl; outp[(size_t)(t + 2) * Cc] = xl;
    xl = (m4.w > 0.f) ? x4.w : xl; outp[(size_t)(t + 3) * Cc] = xl;
  }
}

// ---------------------------------------------------------------------------
// K2: fused gamma_x/gamma_h + xin + input-side pre-GEMM.
// Block = 256 threads, 32 (b,t) rows. Micro-kernel: float4 over k on the
// broadcast operand -> 12 LDS insts / 32 FMA (was ~36/32).
// ---------------------------------------------------------------------------
__global__ __launch_bounds__(256) void k_pre(
    const float* __restrict__ input, const float* __restrict__ x_mean,
    const float* __restrict__ xlast,
    const float* __restrict__ w_dg_x, const float* __restrict__ b_dg_x,
    const float* __restrict__ w_dg_h, const float* __restrict__ b_dg_h,
    const float* __restrict__ w_xz, const float* __restrict__ w_mz, const float* __restrict__ b_mz,
    const float* __restrict__ w_xr, const float* __restrict__ w_mr,
    const float* __restrict__ w_xh, const float* __restrict__ w_mh, const float* __restrict__ b_mh,
    float* __restrict__ gamma_h, float* __restrict__ pre_z,
    float* __restrict__ pre_r, float* __restrict__ pre_h) {
  __shared__ __align__(16) float d_s[32][Cc];     // 8 KB
  __shared__ __align__(16) float m_s[32][Cc];     // 8 KB
  __shared__ __align__(16) float x_s[32][Cc];     // 8 KB
  __shared__ __align__(16) float xin_s[32][Cc];   // 8 KB
  __shared__ __align__(16) float wbuf[8192];      // 32 KB
  const int tid = threadIdx.x;
  const int row0 = blockIdx.x * 32;
  const int b = row0 >> 9;          // / T
  const int t0 = row0 & 511;        // % T

  // stage D, M, X tiles
  #pragma unroll
  for (int i = 0; i < 8; ++i) {
    int e = tid + i * 256;
    int c = e >> 5, tt = e & 31;
    d_s[tt][c] = input[((size_t)(b * 3 + 2) * Cc + c) * Tc + t0 + tt];
    m_s[tt][c] = input[((size_t)(b * 3 + 1) * Cc + c) * Tc + t0 + tt];
    x_s[tt][c] = input[((size_t)(b * 3 + 0) * Cc + c) * Tc + t0 + tt];
  }

  const int col = tid & 63, rbase = tid >> 6;

  // -------- Phase A: gamma chunks (0: gamma_x->xin, 1,2: gamma_h halves) ----
  for (int ch = 0; ch < 3; ++ch) {
    __syncthreads();
    #pragma unroll
    for (int i = 0; i < 16; ++i) {
      int e = tid + i * 256;                 // 0..4095
      int k = e >> 6, c = e & 63;
      wbuf[e] = (ch == 0) ? w_dg_x[k * Cc + c]
                          : w_dg_h[k * Hc + (ch - 1) * 64 + c];
    }
    __syncthreads();
    float bias = (ch == 0) ? b_dg_x[col] : b_dg_h[(ch - 1) * 64 + col];
    float acc[8] = {bias, bias, bias, bias, bias, bias, bias, bias};
    #pragma unroll 4
    for (int k4 = 0; k4 < 64; k4 += 4) {
      float w0 = wbuf[(k4 + 0) * 64 + col];
      float w1 = wbuf[(k4 + 1) * 64 + col];
      float w2 = wbuf[(k4 + 2) * 64 + col];
      float w3 = wbuf[(k4 + 3) * 64 + col];
      #pragma unroll
      for (int r = 0; r < 8; ++r) {
        const float4 dv = *reinterpret_cast<const float4*>(&d_s[rbase + r * 4][k4]);
        acc[r] += dv.x * w0 + dv.y * w1 + dv.z * w2 + dv.w * w3;
      }
    }
    if (ch == 0) {
      float xmn = x_mean[b * Cc + col];
      #pragma unroll
      for (int r = 0; r < 8; ++r) {
        int row = rbase + r * 4;
        float g = __expf(-fmaxf(acc[r], 0.f));
        float mv = m_s[row][col], xv = x_s[row][col];
        float xlv = xlast[((size_t)(b * Tc + t0 + row)) * Cc + col];
        xin_s[row][col] = mv * xv + (1.f - mv) * (g * xlv + (1.f - g) * xmn);
      }
    } else {
      #pragma unroll
      for (int r = 0; r < 8; ++r) {
        int row = rbase + r * 4;
        gamma_h[((size_t)(b * Tc + t0 + row)) * Hc + (ch - 1) * 64 + col] =
            __expf(-fmaxf(acc[r], 0.f));
      }
    }
  }

  // -------- Phase B: pre_{z,r,h} GEMM, K=128 ([xin|m]), 6 N-chunks of 64 ----
  const float* wxs[3] = {w_xz, w_xr, w_xh};
  const float* wms[3] = {w_mz, w_mr, w_mh};
  float* outs[3] = {pre_z, pre_r, pre_h};
  for (int cc = 0; cc < 6; ++cc) {
    int bufi = cc >> 1, half = cc & 1;
    const float* wxp = wxs[bufi];
    const float* wmp = wms[bufi];
    __syncthreads();
    #pragma unroll
    for (int i = 0; i < 32; ++i) {
      int e = tid + i * 256;                 // 0..8191
      int k = e >> 6, jj = e & 63;
      wbuf[k * 64 + jj] = (k < 64) ? wxp[(size_t)k * Hc + half * 64 + jj]
                                   : wmp[(size_t)(k - 64) * Hc + half * 64 + jj];
    }
    __syncthreads();
    float acc[8] = {0.f, 0.f, 0.f, 0.f, 0.f, 0.f, 0.f, 0.f};
    #pragma unroll 4
    for (int k4 = 0; k4 < 64; k4 += 4) {
      float w0 = wbuf[(k4 + 0) * 64 + col];
      float w1 = wbuf[(k4 + 1) * 64 + col];
      float w2 = wbuf[(k4 + 2) * 64 + col];
      float w3 = wbuf[(k4 + 3) * 64 + col];
      #pragma unroll
      for (int r = 0; r < 8; ++r) {
        const float4 xv = *reinterpret_cast<const float4*>(&xin_s[rbase + r * 4][k4]);
        acc[r] += xv.x * w0 + xv.y * w1 + xv.z * w2 + xv.w * w3;
      }
    }
    #pragma unroll 4
    for (int k4 = 0; k4 < 64; k4 += 4) {
      float w0 = wbuf[(64 + k4 + 0) * 64 + col];
      float w1 = wbuf[(64 + k4 + 1) * 64 + col];
      float w2 = wbuf[(64 + k4 + 2) * 64 + col];
      float w3 = wbuf[(64 + k4 + 3) * 64 + col];
      #pragma unroll
      for (int r = 0; r < 8; ++r) {
        const float4 mv = *reinterpret_cast<const float4*>(&m_s[rbase + r * 4][k4]);
        acc[r] += mv.x * w0 + mv.y * w1 + mv.z * w2 + mv.w * w3;
      }
    }
    float bias = 0.f;
    if (bufi == 0) bias = b_mz[half * 64 + col];
    if (bufi == 2) bias = b_mh[half * 64 + col];
    float* op = outs[bufi];
    #pragma unroll
    for (int r = 0; r < 8; ++r) {
      int row = rbase + r * 4;
      op[((size_t)(b * Tc + t0 + row)) * Hc + half * 64 + col] = acc[r] + bias;
    }
  }
}

// ---------------------------------------------------------------------------
// K3: sequential h-recurrence. One block per b. 768 threads = 3 roles x
// (128 cols x 2 k-halves). Each thread: 64 weights in float4 w[16] (register
// resident, no spill). Pair-reduce via shfl_xor(1). Next-step pre_*/gamma_h
// prefetched into registers. 3 barriers/step.
// ---------------------------------------------------------------------------
__global__ __launch_bounds__(768, 3) void k_seq(
    const float* __restrict__ gamma_h, const float* __restrict__ pre_z,
    const float* __restrict__ pre_r, const float* __restrict__ pre_h,
    const float* __restrict__ w_hz, const float* __restrict__ w_hr,
    const float* __restrict__ w_hh, float* __restrict__ hs_out) {
  const int b = blockIdx.x;
  const int tid = threadIdx.x;
  const int role = tid >> 8;        // 0=z, 1=r, 2=h~   (4 waves per role)
  const int idx  = tid & 255;
  const int col  = idx >> 1;        // 0..127
  const int half = idx & 1;         // k-half
  const int kb   = half * 64;
  const bool owner = (role == 0) && (half == 0);

  __shared__ __align__(16) float hd_s[Hc];
  __shared__ __align__(16) float rhd_s[Hc];
  __shared__ __align__(16) float ht_s[Hc];

  const float* W = (role == 0) ? w_hz : (role == 1) ? w_hr : w_hh;
  float4 w[16];
  #pragma unroll
  for (int i = 0; i < 16; ++i) {
    int k = kb + i * 4;
    w[i].x = W[(size_t)(k + 0) * Hc + col];
    w[i].y = W[(size_t)(k + 1) * Hc + col];
    w[i].z = W[(size_t)(k + 2) * Hc + col];
    w[i].w = W[(size_t)(k + 3) * Hc + col];
  }

  const float* preP = (role == 0) ? pre_z : (role == 1) ? pre_r : pre_h;
  const size_t b0 = (size_t)b * Tc * Hc;

  float h_j = 0.f, z_j = 0.f, hd_j = 0.f;
  float pv = preP[b0 + col];                       // t=0 pre value
  float gv = owner ? gamma_h[b0 + col] : 0.f;      // t=0 gamma

  for (int t = 0; t < Tc; ++t) {
    const size_t base = b0 + (size_t)t * Hc;
    // Phase A (owners): hd
    if (owner) {
      hd_j = gv * h_j;
      hd_s[col] = hd_j;
    }
    __syncthreads();
    // prefetch t+1 (in flight across the dots below)
    float pv_n = 0.f, gv_n = 0.f;
    if (t + 1 < Tc) {
      pv_n = preP[base + Hc + col];
      if (owner) gv_n = gamma_h[base + Hc + col];
    }
    // Phase B: z and r dots
    if (role < 2) {
      float acc = 0.f;
      #pragma unroll
      for (int i = 0; i < 16; ++i) {
        const float4 hv = *reinterpret_cast<const float4*>(&hd_s[kb + i * 4]);
        acc += hv.x * w[i].x + hv.y * w[i].y + hv.z * w[i].z + hv.w * w[i].w;
      }
      acc += __shfl_xor(acc, 1);
      float g = 1.f / (1.f + __expf(-(pv + acc)));
      if (role == 0) z_j = g;
      else if (half == 0) rhd_s[col] = g * hd_s[col];
    }
    __syncthreads();
    // Phase C: h~ dot
    if (role == 2) {
      float acc = 0.f;
      #pragma unroll
      for (int i = 0; i < 16; ++i) {
        const float4 rv = *reinterpret_cast<const float4*>(&rhd_s[kb + i * 4]);
        acc += rv.x * w[i].x + rv.y * w[i].y + rv.z * w[i].z + rv.w * w[i].w;
      }
      acc += __shfl_xor(acc, 1);
      float x2 = pv + acc;
      float e = __expf(-2.f * x2);
      if (half == 0) ht_s[col] = (1.f - e) / (1.f + e);   // tanh
    }
    __syncthreads();
    // Phase D (owners): h update + store
    if (owner) {
      float hn = (1.f - z_j) * hd_j + z_j * ht_s[col];
      h_j = hn;
      hs_out[base + col] = hn;
    }
    pv = pv_n; gv = gv_n;
  }
}

// ---------------------------------------------------------------------------
// K4: ys = sigmoid(hs @ w_hy + b_hy).
// ---------------------------------------------------------------------------
__global__ __launch_bounds__(256) void k_y(const float* __restrict__ hs,
                                           const float* __restrict__ w_hy,
                                           const float* __restrict__ b_hy,
                                           float* __restrict__ ys) {
  __shared__ __align__(16) float wy_s[Hc * Oc];   // 32 KB
  __shared__ __align__(16) float hh_s[32][Hc];    // 16 KB
  const int tid = threadIdx.x;
  const int row0 = blockIdx.x * 32;
  #pragma unroll
  for (int i = 0; i < 32; ++i) {
    int e = tid + i * 256;          // 0..8191
    wy_s[e] = w_hy[e];
  }
  #pragma unroll
  for (int i = 0; i < 16; ++i) {
    int e = tid + i * 256;          // 0..4095
    int r = e >> 7, k = e & 127;
    hh_s[r][k] = hs[((size_t)(row0 + r)) * Hc + k];
  }
  __syncthreads();
  int col = tid & 63, rbase = tid >> 6;
  float acc[8] = {0.f, 0.f, 0.f, 0.f, 0.f, 0.f, 0.f, 0.f};
  #pragma unroll 4
  for (int k4 = 0; k4 < Hc; k4 += 4) {
    float w0 = wy_s[(k4 + 0) * Oc + col];
    float w1 = wy_s[(k4 + 1) * Oc + col];
    float w2 = wy_s[(k4 + 2) * Oc + col];
    float w3 = wy_s[(k4 + 3) * Oc + col];
    #pragma unroll
    for (int r = 0; r < 8; ++r) {
      const float4 hv = *reinterpret_cast<const float4*>(&hh_s[rbase + r * 4][k4]);
      acc[r] += hv.x * w0 + hv.y * w1 + hv.z * w2 + hv.w * w3;
    }
  }
  float bias = b_hy[col];
  #pragma unroll
  for (int r = 0; r < 8; ++r) {
    int row = rbase + r * 4;
    ys[((size_t)(row0 + row)) * Oc + col] = 1.f / (1.f + __expf(-(acc[r] + bias)));
  }
}

// ---------------------------------------------------------------------------
extern "C" void kernel_launch(void* const* d_in, const int* in_sizes, int n_in,
                              void* d_out, int out_size, void* d_ws, size_t ws_size,
                              hipStream_t stream) {
  const float* input  = (const float*)d_in[0];
  const float* x_mean = (const float*)d_in[1];
  const float* lastx  = (const float*)d_in[2];
  const float* w_dg_x = (const float*)d_in[3];
  const float* b_dg_x = (const float*)d_in[4];
  const float* w_dg_h = (const float*)d_in[5];
  const float* b_dg_h = (const float*)d_in[6];
  const float* w_xz   = (const float*)d_in[7];
  const float* w_hz   = (const float*)d_in[8];
  const float* w_mz   = (const float*)d_in[9];
  const float* b_mz   = (const float*)d_in[10];
  const float* w_xr   = (const float*)d_in[11];
  const float* w_hr   = (const float*)d_in[12];
  const float* w_mr   = (const float*)d_in[13];
  const float* w_xh   = (const float*)d_in[14];
  const float* w_hh   = (const float*)d_in[15];
  const float* w_mh   = (const float*)d_in[16];
  const float* b_mh   = (const float*)d_in[17];
  const float* w_hy   = (const float*)d_in[18];
  const float* b_hy   = (const float*)d_in[19];

  float* ys = (float*)d_out;                          // (B,T,O)
  float* hs = (float*)d_out + (size_t)Bc * Tc * Oc;   // (B,T,H)

  float* ws      = (float*)d_ws;
  float* xlast   = ws;                                      // B*T*C
  float* gamma_h = xlast + (size_t)Bc * Tc * Cc;            // B*T*H
  float* pre_z   = gamma_h + (size_t)Bc * Tc * Hc;          // B*T*H
  float* pre_r   = pre_z + (size_t)Bc * Tc * Hc;            // B*T*H
  float* pre_h   = pre_r + (size_t)Bc * Tc * Hc;            // B*T*H

  k_scan<<<(Bc * Cc) / 256, 256, 0, stream>>>(input, lastx, xlast);
  k_pre<<<(Bc * Tc) / 32, 256, 0, stream>>>(input, x_mean, xlast,
                                            w_dg_x, b_dg_x, w_dg_h, b_dg_h,
                                            w_xz, w_mz, b_mz, w_xr, w_mr,
                                            w_xh, w_mh, b_mh,
                                            gamma_h, pre_z, pre_r, pre_h);
  k_seq<<<Bc, 768, 0, stream>>>(gamma_h, pre_z, pre_r, pre_h,
                                w_hz, w_hr, w_hh, hs);
  k_y<<<(Bc * Tc) / 32, 256, 0, stream>>>(hs, w_hy, b_hy, ys);
}

// Round 3
// 1026.803 us; speedup vs baseline: 3.4594x; 1.8379x over previous
//
#include <hip/hip_runtime.h>
#include <cstdint>

#define Bc 256
#define Cc 64
#define Hc 128
#define Oc 64
#define Tc 512

typedef short bf16x8 __attribute__((ext_vector_type(8)));
typedef float f32x4 __attribute__((ext_vector_type(4)));

static __device__ __forceinline__ unsigned short f2b(float f) {
  unsigned u = __float_as_uint(f);
  unsigned r = u + 0x7FFFu + ((u >> 16) & 1u);   // RNE
  return (unsigned short)(r >> 16);
}

// ---------------------------------------------------------------------------
// K0: weight prep — transpose + bf16-convert all GEMM weights into d_ws.
//  wdgT [192][64]  : n<64 -> w_dg_x[:,n] ; n>=64 -> w_dg_h[:,n-64]
//  w2T  [384][128] : n = gate*128+nc (z,r,h); k<64 -> w_x*[k][nc], k>=64 -> w_m*[k-64][nc]
//  hyT  [64][128]  : w_hy[:,n]
// ---------------------------------------------------------------------------
__global__ __launch_bounds__(256) void k_wprep(
    const float* __restrict__ w_dg_x, const float* __restrict__ w_dg_h,
    const float* __restrict__ w_xz, const float* __restrict__ w_mz,
    const float* __restrict__ w_xr, const float* __restrict__ w_mr,
    const float* __restrict__ w_xh, const float* __restrict__ w_mh,
    const float* __restrict__ w_hy,
    unsigned short* __restrict__ wdgT, unsigned short* __restrict__ w2T,
    unsigned short* __restrict__ hyT) {
  int e = blockIdx.x * 256 + threadIdx.x;
  if (e < 12288) {                       // wdgT: 192 x 64
    int n = e >> 6, k = e & 63;
    float v = (n < 64) ? w_dg_x[k * Cc + n] : w_dg_h[k * Hc + (n - 64)];
    wdgT[e] = f2b(v);
  } else if (e < 61440) {                // w2T: 384 x 128
    int i = e - 12288;
    int n = i >> 7, k = i & 127;
    int gate = n >> 7, nc = n & 127;
    const float* wx = (gate == 0) ? w_xz : (gate == 1) ? w_xr : w_xh;
    const float* wm = (gate == 0) ? w_mz : (gate == 1) ? w_mr : w_mh;
    float v = (k < 64) ? wx[k * Hc + nc] : wm[(k - 64) * Hc + nc];
    w2T[i] = f2b(v);
  } else if (e < 69632) {                // hyT: 64 x 128
    int i = e - 61440;
    int n = i >> 7, k = i & 127;
    hyT[i] = f2b(w_hy[k * Oc + n]);
  }
}

// ---------------------------------------------------------------------------
// K1: segmented x_last select-scan. One block per b; 4 segments x 64 c.
// Phase1: backward early-exit search for last observation per segment.
// Phase2: serial combine over 4 segments. Phase3: forward replay + write.
// ---------------------------------------------------------------------------
__global__ __launch_bounds__(256) void k_scan(const float* __restrict__ input,
                                              const float* __restrict__ lastx,
                                              float* __restrict__ xlast) {
  const int b = blockIdx.x;
  const int seg = threadIdx.x >> 6;      // 0..3, whole wave same seg
  const int c = threadIdx.x & 63;
  const int tb = seg * 128;
  __shared__ float segval[4][64];
  __shared__ int   segvld[4][64];
  __shared__ float segcin[4][64];
  const float* xp = input + ((size_t)(b * 3 + 0) * Cc + c) * Tc;
  const float* mp = input + ((size_t)(b * 3 + 1) * Cc + c) * Tc;

  float val = 0.f; int vld = 0;
  for (int t = tb + 127; t >= tb; --t) {
    if (mp[t] > 0.f) { val = xp[t]; vld = 1; break; }
  }
  segval[seg][c] = val; segvld[seg][c] = vld;
  __syncthreads();
  if (threadIdx.x < 64) {
    float carry = lastx[b * Cc + threadIdx.x];
    #pragma unroll
    for (int s = 0; s < 4; ++s) {
      segcin[s][threadIdx.x] = carry;
      if (segvld[s][threadIdx.x]) carry = segval[s][threadIdx.x];
    }
  }
  __syncthreads();
  float cur = segcin[seg][c];
  float* op = xlast + ((size_t)b * Tc + tb) * Cc + c;
  for (int t = 0; t < 128; t += 4) {
    const float4 m4 = *reinterpret_cast<const float4*>(mp + tb + t);
    const float4 x4 = *reinterpret_cast<const float4*>(xp + tb + t);
    cur = (m4.x > 0.f) ? x4.x : cur; op[(size_t)(t + 0) * Cc] = cur;
    cur = (m4.y > 0.f) ? x4.y : cur; op[(size_t)(t + 1) * Cc] = cur;
    cur = (m4.z > 0.f) ? x4.z : cur; op[(size_t)(t + 2) * Cc] = cur;
    cur = (m4.w > 0.f) ? x4.w : cur; op[(size_t)(t + 3) * Cc] = cur;
  }
}

// ---------------------------------------------------------------------------
// K2: MFMA bf16 pre-compute. Block = 64 rows (one b, 64 t's), 256 thr = 4 waves.
// GEMM-A: D(64x64) @ WdgT(192 cols) -> gamma epilogue -> xin -> A16.
// GEMM-B: [xin|m](64x128) @ w2T(384 cols) -> pre_z/r/h (+bias) fp32.
// LDS pitches chosen for conflict-free b128 frag reads (4*(m+quad) mod 32).
// ---------------------------------------------------------------------------
__global__ __launch_bounds__(256) void k_pre(
    const float* __restrict__ input, const float* __restrict__ x_mean,
    const float* __restrict__ xlast,
    const float* __restrict__ b_dg_x, const float* __restrict__ b_dg_h,
    const float* __restrict__ b_mz, const float* __restrict__ b_mh,
    const unsigned short* __restrict__ wdgT, const unsigned short* __restrict__ w2T,
    float* __restrict__ gamma_h, float* __restrict__ pre_z,
    float* __restrict__ pre_r, float* __restrict__ pre_h) {
  __shared__ unsigned short d16[64 * 72];            // 9216 B, A of GEMM-A
  __shared__ unsigned short A16[64 * 136];           // 17408 B, [xin(0:64)|m(64:128)]
  __shared__ float x_cs[64 * 68];                    // 17408 B, [c][t]
  __shared__ float m_cs[64 * 68];                    // 17408 B, [c][t]

  const int tid = threadIdx.x;
  const int b = blockIdx.x >> 3;
  const int t0 = (blockIdx.x & 7) * 64;
  const int w = tid >> 6, lane = tid & 63, quad = lane >> 4, l16 = lane & 15;

  // ---- stage x, m, d (coalesced float4 along t) ----
  #pragma unroll
  for (int i = 0; i < 4; ++i) {
    int e = tid + i * 256;                 // 0..1023
    int c = e >> 4, t4 = (e & 15) * 4;
    const size_t rx = ((size_t)(b * 3 + 0) * Cc + c) * Tc + t0 + t4;
    const size_t rm = ((size_t)(b * 3 + 1) * Cc + c) * Tc + t0 + t4;
    const size_t rd = ((size_t)(b * 3 + 2) * Cc + c) * Tc + t0 + t4;
    float4 xv = *reinterpret_cast<const float4*>(input + rx);
    float4 mv = *reinterpret_cast<const float4*>(input + rm);
    float4 dv = *reinterpret_cast<const float4*>(input + rd);
    *reinterpret_cast<float4*>(&x_cs[c * 68 + t4]) = xv;
    *reinterpret_cast<float4*>(&m_cs[c * 68 + t4]) = mv;
    A16[(t4 + 0) * 136 + 64 + c] = f2b(mv.x);
    A16[(t4 + 1) * 136 + 64 + c] = f2b(mv.y);
    A16[(t4 + 2) * 136 + 64 + c] = f2b(mv.z);
    A16[(t4 + 3) * 136 + 64 + c] = f2b(mv.w);
    d16[(t4 + 0) * 72 + c] = f2b(dv.x);
    d16[(t4 + 1) * 72 + c] = f2b(dv.y);
    d16[(t4 + 2) * 72 + c] = f2b(dv.z);
    d16[(t4 + 3) * 72 + c] = f2b(dv.w);
  }
  __syncthreads();

  // ---- GEMM-A: wave w owns n-tiles {w, w+4, w+8} ----
  f32x4 accA[4][3];
  #pragma unroll
  for (int mt = 0; mt < 4; ++mt)
    #pragma unroll
    for (int j = 0; j < 3; ++j) accA[mt][j] = {0.f, 0.f, 0.f, 0.f};
  #pragma unroll
  for (int kt = 0; kt < 2; ++kt) {
    bf16x8 a[4];
    #pragma unroll
    for (int mt = 0; mt < 4; ++mt)
      a[mt] = *reinterpret_cast<const bf16x8*>(&d16[(mt * 16 + l16) * 72 + kt * 32 + quad * 8]);
    #pragma unroll
    for (int j = 0; j < 3; ++j) {
      int nt = w + j * 4;
      bf16x8 bb = *reinterpret_cast<const bf16x8*>(wdgT + (nt * 16 + l16) * 64 + kt * 32 + quad * 8);
      #pragma unroll
      for (int mt = 0; mt < 4; ++mt)
        accA[mt][j] = __builtin_amdgcn_mfma_f32_16x16x32_bf16(a[mt], bb, accA[mt][j], 0, 0, 0);
    }
  }

  // ---- epilogue A, j=0: gamma_x -> xin (bf16 into A16) ----
  {
    int c = w * 16 + l16;
    float xmn = x_mean[b * Cc + c];
    float bx = b_dg_x[c];
    #pragma unroll
    for (int mt = 0; mt < 4; ++mt)
      #pragma unroll
      for (int r = 0; r < 4; ++r) {
        int row = mt * 16 + quad * 4 + r;
        float g = __expf(-fmaxf(accA[mt][0][r] + bx, 0.f));
        float mv = m_cs[c * 68 + row], xv = x_cs[c * 68 + row];
        float xl = xlast[((size_t)b * Tc + t0 + row) * Cc + c];
        float xin = mv * xv + (1.f - mv) * (g * xl + (1.f - g) * xmn);
        A16[row * 136 + c] = f2b(xin);
      }
  }
  // ---- epilogue A, j=1,2: gamma_h -> global fp32 ----
  #pragma unroll
  for (int j = 1; j < 3; ++j) {
    int nh = (w + j * 4) * 16 - 64 + l16;   // 0..127
    float bh = b_dg_h[nh];
    #pragma unroll
    for (int mt = 0; mt < 4; ++mt)
      #pragma unroll
      for (int r = 0; r < 4; ++r) {
        int row = mt * 16 + quad * 4 + r;
        gamma_h[((size_t)b * Tc + t0 + row) * Hc + nh] =
            __expf(-fmaxf(accA[mt][j][r] + bh, 0.f));
      }
  }
  __syncthreads();

  // ---- GEMM-B: wave w owns nt = {gate*8 + w, gate*8 + w + 4} ----
  f32x4 accB[4][6];
  #pragma unroll
  for (int mt = 0; mt < 4; ++mt)
    #pragma unroll
    for (int j = 0; j < 6; ++j) accB[mt][j] = {0.f, 0.f, 0.f, 0.f};
  #pragma unroll
  for (int kt = 0; kt < 4; ++kt) {
    bf16x8 a[4];
    #pragma unroll
    for (int mt = 0; mt < 4; ++mt)
      a[mt] = *reinterpret_cast<const bf16x8*>(&A16[(mt * 16 + l16) * 136 + kt * 32 + quad * 8]);
    #pragma unroll
    for (int j = 0; j < 6; ++j) {
      int nt = (j >> 1) * 8 + w + (j & 1) * 4;
      bf16x8 bb = *reinterpret_cast<const bf16x8*>(w2T + (nt * 16 + l16) * 128 + kt * 32 + quad * 8);
      #pragma unroll
      for (int mt = 0; mt < 4; ++mt)
        accB[mt][j] = __builtin_amdgcn_mfma_f32_16x16x32_bf16(a[mt], bb, accB[mt][j], 0, 0, 0);
    }
  }
  // ---- epilogue B ----
  #pragma unroll
  for (int j = 0; j < 6; ++j) {
    int nt = (j >> 1) * 8 + w + (j & 1) * 4;
    int gate = nt >> 3;
    int col = (nt & 7) * 16 + l16;
    float bias = (gate == 0) ? b_mz[col] : (gate == 2) ? b_mh[col] : 0.f;
    float* op = (gate == 0) ? pre_z : (gate == 1) ? pre_r : pre_h;
    #pragma unroll
    for (int mt = 0; mt < 4; ++mt)
      #pragma unroll
      for (int r = 0; r < 4; ++r) {
        int row = mt * 16 + quad * 4 + r;
        op[((size_t)b * Tc + t0 + row) * Hc + col] = accB[mt][j][r] + bias;
      }
  }
}

// ---------------------------------------------------------------------------
// K3: sequential h-recurrence (unchanged from R2 — fp32, register weights).
// ---------------------------------------------------------------------------
__global__ __launch_bounds__(768, 3) void k_seq(
    const float* __restrict__ gamma_h, const float* __restrict__ pre_z,
    const float* __restrict__ pre_r, const float* __restrict__ pre_h,
    const float* __restrict__ w_hz, const float* __restrict__ w_hr,
    const float* __restrict__ w_hh, float* __restrict__ hs_out) {
  const int b = blockIdx.x;
  const int tid = threadIdx.x;
  const int role = tid >> 8;
  const int idx  = tid & 255;
  const int col  = idx >> 1;
  const int half = idx & 1;
  const int kb   = half * 64;
  const bool owner = (role == 0) && (half == 0);

  __shared__ __align__(16) float hd_s[Hc];
  __shared__ __align__(16) float rhd_s[Hc];
  __shared__ __align__(16) float ht_s[Hc];

  const float* W = (role == 0) ? w_hz : (role == 1) ? w_hr : w_hh;
  float4 w[16];
  #pragma unroll
  for (int i = 0; i < 16; ++i) {
    int k = kb + i * 4;
    w[i].x = W[(size_t)(k + 0) * Hc + col];
    w[i].y = W[(size_t)(k + 1) * Hc + col];
    w[i].z = W[(size_t)(k + 2) * Hc + col];
    w[i].w = W[(size_t)(k + 3) * Hc + col];
  }

  const float* preP = (role == 0) ? pre_z : (role == 1) ? pre_r : pre_h;
  const size_t b0 = (size_t)b * Tc * Hc;

  float h_j = 0.f, z_j = 0.f, hd_j = 0.f;
  float pv = preP[b0 + col];
  float gv = owner ? gamma_h[b0 + col] : 0.f;

  for (int t = 0; t < Tc; ++t) {
    const size_t base = b0 + (size_t)t * Hc;
    if (owner) {
      hd_j = gv * h_j;
      hd_s[col] = hd_j;
    }
    __syncthreads();
    float pv_n = 0.f, gv_n = 0.f;
    if (t + 1 < Tc) {
      pv_n = preP[base + Hc + col];
      if (owner) gv_n = gamma_h[base + Hc + col];
    }
    if (role < 2) {
      float acc = 0.f;
      #pragma unroll
      for (int i = 0; i < 16; ++i) {
        const float4 hv = *reinterpret_cast<const float4*>(&hd_s[kb + i * 4]);
        acc += hv.x * w[i].x + hv.y * w[i].y + hv.z * w[i].z + hv.w * w[i].w;
      }
      acc += __shfl_xor(acc, 1);
      float g = 1.f / (1.f + __expf(-(pv + acc)));
      if (role == 0) z_j = g;
      else if (half == 0) rhd_s[col] = g * hd_s[col];
    }
    __syncthreads();
    if (role == 2) {
      float acc = 0.f;
      #pragma unroll
      for (int i = 0; i < 16; ++i) {
        const float4 rv = *reinterpret_cast<const float4*>(&rhd_s[kb + i * 4]);
        acc += rv.x * w[i].x + rv.y * w[i].y + rv.z * w[i].z + rv.w * w[i].w;
      }
      acc += __shfl_xor(acc, 1);
      float x2 = pv + acc;
      float e = __expf(-2.f * x2);
      if (half == 0) ht_s[col] = (1.f - e) / (1.f + e);
    }
    __syncthreads();
    if (owner) {
      float hn = (1.f - z_j) * hd_j + z_j * ht_s[col];
      h_j = hn;
      hs_out[base + col] = hn;
    }
    pv = pv_n; gv = gv_n;
  }
}

// ---------------------------------------------------------------------------
// K4: ys = sigmoid(hs @ w_hy + b_hy) via MFMA bf16. 64 rows/block.
// ---------------------------------------------------------------------------
__global__ __launch_bounds__(256) void k_y(const float* __restrict__ hs,
                                           const unsigned short* __restrict__ hyT,
                                           const float* __restrict__ b_hy,
                                           float* __restrict__ ys) {
  __shared__ unsigned short A16[64 * 136];
  const int tid = threadIdx.x;
  const int r0 = blockIdx.x * 64;
  const int w = tid >> 6, lane = tid & 63, quad = lane >> 4, l16 = lane & 15;

  #pragma unroll
  for (int i = 0; i < 8; ++i) {
    int e = tid + i * 256;                 // 0..2047
    int row = e >> 5, k4 = (e & 31) * 4;
    float4 hv = *reinterpret_cast<const float4*>(&hs[(size_t)(r0 + row) * Hc + k4]);
    unsigned short s0 = f2b(hv.x), s1 = f2b(hv.y), s2 = f2b(hv.z), s3 = f2b(hv.w);
    unsigned int lo = (unsigned int)s0 | ((unsigned int)s1 << 16);
    unsigned int hi = (unsigned int)s2 | ((unsigned int)s3 << 16);
    *reinterpret_cast<uint2*>(&A16[row * 136 + k4]) = make_uint2(lo, hi);
  }
  __syncthreads();

  f32x4 acc[4];
  #pragma unroll
  for (int mt = 0; mt < 4; ++mt) acc[mt] = {0.f, 0.f, 0.f, 0.f};
  #pragma unroll
  for (int kt = 0; kt < 4; ++kt) {
    bf16x8 bb = *reinterpret_cast<const bf16x8*>(hyT + (w * 16 + l16) * 128 + kt * 32 + quad * 8);
    #pragma unroll
    for (int mt = 0; mt < 4; ++mt) {
      bf16x8 a = *reinterpret_cast<const bf16x8*>(&A16[(mt * 16 + l16) * 136 + kt * 32 + quad * 8]);
      acc[mt] = __builtin_amdgcn_mfma_f32_16x16x32_bf16(a, bb, acc[mt], 0, 0, 0);
    }
  }
  int col = w * 16 + l16;
  float bias = b_hy[col];
  #pragma unroll
  for (int mt = 0; mt < 4; ++mt)
    #pragma unroll
    for (int r = 0; r < 4; ++r) {
      int row = mt * 16 + quad * 4 + r;
      ys[(size_t)(r0 + row) * Oc + col] = 1.f / (1.f + __expf(-(acc[mt][r] + bias)));
    }
}

// ---------------------------------------------------------------------------
extern "C" void kernel_launch(void* const* d_in, const int* in_sizes, int n_in,
                              void* d_out, int out_size, void* d_ws, size_t ws_size,
                              hipStream_t stream) {
  const float* input  = (const float*)d_in[0];
  const float* x_mean = (const float*)d_in[1];
  const float* lastx  = (const float*)d_in[2];
  const float* w_dg_x = (const float*)d_in[3];
  const float* b_dg_x = (const float*)d_in[4];
  const float* w_dg_h = (const float*)d_in[5];
  const float* b_dg_h = (const float*)d_in[6];
  const float* w_xz   = (const float*)d_in[7];
  const float* w_hz   = (const float*)d_in[8];
  const float* w_mz   = (const float*)d_in[9];
  const float* b_mz   = (const float*)d_in[10];
  const float* w_xr   = (const float*)d_in[11];
  const float* w_hr   = (const float*)d_in[12];
  const float* w_mr   = (const float*)d_in[13];
  const float* w_xh   = (const float*)d_in[14];
  const float* w_hh   = (const float*)d_in[15];
  const float* w_mh   = (const float*)d_in[16];
  const float* b_mh   = (const float*)d_in[17];
  const float* w_hy   = (const float*)d_in[18];
  const float* b_hy   = (const float*)d_in[19];

  float* ys = (float*)d_out;                          // (B,T,O)
  float* hs = (float*)d_out + (size_t)Bc * Tc * Oc;   // (B,T,H)

  float* ws      = (float*)d_ws;
  float* xlast   = ws;                                      // B*T*C
  float* gamma_h = xlast + (size_t)Bc * Tc * Cc;            // B*T*H
  float* pre_z   = gamma_h + (size_t)Bc * Tc * Hc;          // B*T*H
  float* pre_r   = pre_z + (size_t)Bc * Tc * Hc;            // B*T*H
  float* pre_h   = pre_r + (size_t)Bc * Tc * Hc;            // B*T*H
  unsigned short* wdgT = (unsigned short*)(pre_h + (size_t)Bc * Tc * Hc); // 192*64
  unsigned short* w2T  = wdgT + 192 * 64;                   // 384*128
  unsigned short* hyT  = w2T + 384 * 128;                   // 64*128

  k_wprep<<<272, 256, 0, stream>>>(w_dg_x, w_dg_h, w_xz, w_mz, w_xr, w_mr,
                                   w_xh, w_mh, w_hy, wdgT, w2T, hyT);
  k_scan<<<Bc, 256, 0, stream>>>(input, lastx, xlast);
  k_pre<<<(Bc * Tc) / 64, 256, 0, stream>>>(input, x_mean, xlast,
                                            b_dg_x, b_dg_h, b_mz, b_mh,
                                            wdgT, w2T,
                                            gamma_h, pre_z, pre_r, pre_h);
  k_seq<<<Bc, 768, 0, stream>>>(gamma_h, pre_z, pre_r, pre_h,
                                w_hz, w_hr, w_hh, hs);
  k_y<<<(Bc * Tc) / 64, 256, 0, stream>>>(hs, hyT, b_hy, ys);
}

// Round 4
// 780.484 us; speedup vs baseline: 4.5512x; 1.3156x over previous
//
#include <hip/hip_runtime.h>
#include <cstdint>

#define Bc 256
#define Cc 64
#define Hc 128
#define Oc 64
#define Tc 512

typedef short bf16x8 __attribute__((ext_vector_type(8)));
typedef float f32x4 __attribute__((ext_vector_type(4)));
typedef _Float16 h2v __attribute__((ext_vector_type(2)));

static __device__ __forceinline__ unsigned short f2b(float f) {
  unsigned u = __float_as_uint(f);
  unsigned r = u + 0x7FFFu + ((u >> 16) & 1u);   // RNE
  return (unsigned short)(r >> 16);
}

// packed fp16 dot2 with fp32 accumulate (v_dot2_f32_f16)
static __device__ __forceinline__ float dot2f(unsigned int a, unsigned int b, float c) {
  h2v av = __builtin_bit_cast(h2v, a);
  h2v bv = __builtin_bit_cast(h2v, b);
#if __has_builtin(__builtin_amdgcn_fdot2)
  return __builtin_amdgcn_fdot2(av, bv, c, false);
#else
  return c + (float)av[0] * (float)bv[0] + (float)av[1] * (float)bv[1];
#endif
}

static __device__ __forceinline__ float sigf(float x) {
  return 1.f / (1.f + __expf(-x));   // overflow-safe: exp->inf -> 0
}

// ---------------------------------------------------------------------------
// K0: weight prep.
//  wdgT [192][64] bf16, w2T [384][128] bf16, hyT [64][128] bf16 (as before)
//  whT  [3][128][64] packed-fp16 pairs: [g][j][kk] = (w_h*[2kk][j], w_h*[2kk+1][j])
// ---------------------------------------------------------------------------
__global__ __launch_bounds__(256) void k_wprep(
    const float* __restrict__ w_dg_x, const float* __restrict__ w_dg_h,
    const float* __restrict__ w_xz, const float* __restrict__ w_mz,
    const float* __restrict__ w_xr, const float* __restrict__ w_mr,
    const float* __restrict__ w_xh, const float* __restrict__ w_mh,
    const float* __restrict__ w_hy,
    const float* __restrict__ w_hz, const float* __restrict__ w_hr,
    const float* __restrict__ w_hh,
    unsigned short* __restrict__ wdgT, unsigned short* __restrict__ w2T,
    unsigned short* __restrict__ hyT, unsigned int* __restrict__ whT) {
  int e = blockIdx.x * 256 + threadIdx.x;
  if (e < 12288) {                       // wdgT: 192 x 64
    int n = e >> 6, k = e & 63;
    float v = (n < 64) ? w_dg_x[k * Cc + n] : w_dg_h[k * Hc + (n - 64)];
    wdgT[e] = f2b(v);
  } else if (e < 61440) {                // w2T: 384 x 128
    int i = e - 12288;
    int n = i >> 7, k = i & 127;
    int gate = n >> 7, nc = n & 127;
    const float* wx = (gate == 0) ? w_xz : (gate == 1) ? w_xr : w_xh;
    const float* wm = (gate == 0) ? w_mz : (gate == 1) ? w_mr : w_mh;
    float v = (k < 64) ? wx[k * Hc + nc] : wm[(k - 64) * Hc + nc];
    w2T[i] = f2b(v);
  } else if (e < 69632) {                // hyT: 64 x 128
    int i = e - 61440;
    int n = i >> 7, k = i & 127;
    hyT[i] = f2b(w_hy[k * Oc + n]);
  } else if (e < 94208) {                // whT: 3 x 128 x 64 packed fp16
    int i = e - 69632;
    int g = i >> 13, rem = i & 8191;
    int j = rem >> 6, kk = rem & 63;
    const float* wh_ = (g == 0) ? w_hz : (g == 1) ? w_hr : w_hh;
    h2v p;
    p[0] = (_Float16)wh_[(2 * kk) * Hc + j];
    p[1] = (_Float16)wh_[(2 * kk + 1) * Hc + j];
    whT[i] = __builtin_bit_cast(unsigned int, p);
  }
}

// ---------------------------------------------------------------------------
// K1: segmented x_last select-scan (unchanged).
// ---------------------------------------------------------------------------
__global__ __launch_bounds__(256) void k_scan(const float* __restrict__ input,
                                              const float* __restrict__ lastx,
                                              float* __restrict__ xlast) {
  const int b = blockIdx.x;
  const int seg = threadIdx.x >> 6;
  const int c = threadIdx.x & 63;
  const int tb = seg * 128;
  __shared__ float segval[4][64];
  __shared__ int   segvld[4][64];
  __shared__ float segcin[4][64];
  const float* xp = input + ((size_t)(b * 3 + 0) * Cc + c) * Tc;
  const float* mp = input + ((size_t)(b * 3 + 1) * Cc + c) * Tc;

  float val = 0.f; int vld = 0;
  for (int t = tb + 127; t >= tb; --t) {
    if (mp[t] > 0.f) { val = xp[t]; vld = 1; break; }
  }
  segval[seg][c] = val; segvld[seg][c] = vld;
  __syncthreads();
  if (threadIdx.x < 64) {
    float carry = lastx[b * Cc + threadIdx.x];
    #pragma unroll
    for (int s = 0; s < 4; ++s) {
      segcin[s][threadIdx.x] = carry;
      if (segvld[s][threadIdx.x]) carry = segval[s][threadIdx.x];
    }
  }
  __syncthreads();
  float cur = segcin[seg][c];
  float* op = xlast + ((size_t)b * Tc + tb) * Cc + c;
  for (int t = 0; t < 128; t += 4) {
    const float4 m4 = *reinterpret_cast<const float4*>(mp + tb + t);
    const float4 x4 = *reinterpret_cast<const float4*>(xp + tb + t);
    cur = (m4.x > 0.f) ? x4.x : cur; op[(size_t)(t + 0) * Cc] = cur;
    cur = (m4.y > 0.f) ? x4.y : cur; op[(size_t)(t + 1) * Cc] = cur;
    cur = (m4.z > 0.f) ? x4.z : cur; op[(size_t)(t + 2) * Cc] = cur;
    cur = (m4.w > 0.f) ? x4.w : cur; op[(size_t)(t + 3) * Cc] = cur;
  }
}

// ---------------------------------------------------------------------------
// K2: MFMA bf16 pre-compute (as R3), now writing fp16 gamma_h / pre_{z,r,h}.
// ---------------------------------------------------------------------------
__global__ __launch_bounds__(256) void k_pre(
    const float* __restrict__ input, const float* __restrict__ x_mean,
    const float* __restrict__ xlast,
    const float* __restrict__ b_dg_x, const float* __restrict__ b_dg_h,
    const float* __restrict__ b_mz, const float* __restrict__ b_mh,
    const unsigned short* __restrict__ wdgT, const unsigned short* __restrict__ w2T,
    _Float16* __restrict__ gamma_h, _Float16* __restrict__ pre_z,
    _Float16* __restrict__ pre_r, _Float16* __restrict__ pre_h) {
  __shared__ unsigned short d16[64 * 72];
  __shared__ unsigned short A16[64 * 136];
  __shared__ float x_cs[64 * 68];
  __shared__ float m_cs[64 * 68];

  const int tid = threadIdx.x;
  const int b = blockIdx.x >> 3;
  const int t0 = (blockIdx.x & 7) * 64;
  const int w = tid >> 6, lane = tid & 63, quad = lane >> 4, l16 = lane & 15;

  #pragma unroll
  for (int i = 0; i < 4; ++i) {
    int e = tid + i * 256;
    int c = e >> 4, t4 = (e & 15) * 4;
    const size_t rx = ((size_t)(b * 3 + 0) * Cc + c) * Tc + t0 + t4;
    const size_t rm = ((size_t)(b * 3 + 1) * Cc + c) * Tc + t0 + t4;
    const size_t rd = ((size_t)(b * 3 + 2) * Cc + c) * Tc + t0 + t4;
    float4 xv = *reinterpret_cast<const float4*>(input + rx);
    float4 mv = *reinterpret_cast<const float4*>(input + rm);
    float4 dv = *reinterpret_cast<const float4*>(input + rd);
    *reinterpret_cast<float4*>(&x_cs[c * 68 + t4]) = xv;
    *reinterpret_cast<float4*>(&m_cs[c * 68 + t4]) = mv;
    A16[(t4 + 0) * 136 + 64 + c] = f2b(mv.x);
    A16[(t4 + 1) * 136 + 64 + c] = f2b(mv.y);
    A16[(t4 + 2) * 136 + 64 + c] = f2b(mv.z);
    A16[(t4 + 3) * 136 + 64 + c] = f2b(mv.w);
    d16[(t4 + 0) * 72 + c] = f2b(dv.x);
    d16[(t4 + 1) * 72 + c] = f2b(dv.y);
    d16[(t4 + 2) * 72 + c] = f2b(dv.z);
    d16[(t4 + 3) * 72 + c] = f2b(dv.w);
  }
  __syncthreads();

  f32x4 accA[4][3];
  #pragma unroll
  for (int mt = 0; mt < 4; ++mt)
    #pragma unroll
    for (int j = 0; j < 3; ++j) accA[mt][j] = {0.f, 0.f, 0.f, 0.f};
  #pragma unroll
  for (int kt = 0; kt < 2; ++kt) {
    bf16x8 a[4];
    #pragma unroll
    for (int mt = 0; mt < 4; ++mt)
      a[mt] = *reinterpret_cast<const bf16x8*>(&d16[(mt * 16 + l16) * 72 + kt * 32 + quad * 8]);
    #pragma unroll
    for (int j = 0; j < 3; ++j) {
      int nt = w + j * 4;
      bf16x8 bb = *reinterpret_cast<const bf16x8*>(wdgT + (nt * 16 + l16) * 64 + kt * 32 + quad * 8);
      #pragma unroll
      for (int mt = 0; mt < 4; ++mt)
        accA[mt][j] = __builtin_amdgcn_mfma_f32_16x16x32_bf16(a[mt], bb, accA[mt][j], 0, 0, 0);
    }
  }

  {
    int c = w * 16 + l16;
    float xmn = x_mean[b * Cc + c];
    float bx = b_dg_x[c];
    #pragma unroll
    for (int mt = 0; mt < 4; ++mt)
      #pragma unroll
      for (int r = 0; r < 4; ++r) {
        int row = mt * 16 + quad * 4 + r;
        float g = __expf(-fmaxf(accA[mt][0][r] + bx, 0.f));
        float mv = m_cs[c * 68 + row], xv = x_cs[c * 68 + row];
        float xl = xlast[((size_t)b * Tc + t0 + row) * Cc + c];
        float xin = mv * xv + (1.f - mv) * (g * xl + (1.f - g) * xmn);
        A16[row * 136 + c] = f2b(xin);
      }
  }
  #pragma unroll
  for (int j = 1; j < 3; ++j) {
    int nh = (w + j * 4) * 16 - 64 + l16;
    float bh = b_dg_h[nh];
    #pragma unroll
    for (int mt = 0; mt < 4; ++mt)
      #pragma unroll
      for (int r = 0; r < 4; ++r) {
        int row = mt * 16 + quad * 4 + r;
        gamma_h[((size_t)b * Tc + t0 + row) * Hc + nh] =
            (_Float16)__expf(-fmaxf(accA[mt][j][r] + bh, 0.f));
      }
  }
  __syncthreads();

  f32x4 accB[4][6];
  #pragma unroll
  for (int mt = 0; mt < 4; ++mt)
    #pragma unroll
    for (int j = 0; j < 6; ++j) accB[mt][j] = {0.f, 0.f, 0.f, 0.f};
  #pragma unroll
  for (int kt = 0; kt < 4; ++kt) {
    bf16x8 a[4];
    #pragma unroll
    for (int mt = 0; mt < 4; ++mt)
      a[mt] = *reinterpret_cast<const bf16x8*>(&A16[(mt * 16 + l16) * 136 + kt * 32 + quad * 8]);
    #pragma unroll
    for (int j = 0; j < 6; ++j) {
      int nt = (j >> 1) * 8 + w + (j & 1) * 4;
      bf16x8 bb = *reinterpret_cast<const bf16x8*>(w2T + (nt * 16 + l16) * 128 + kt * 32 + quad * 8);
      #pragma unroll
      for (int mt = 0; mt < 4; ++mt)
        accB[mt][j] = __builtin_amdgcn_mfma_f32_16x16x32_bf16(a[mt], bb, accB[mt][j], 0, 0, 0);
    }
  }
  #pragma unroll
  for (int j = 0; j < 6; ++j) {
    int nt = (j >> 1) * 8 + w + (j & 1) * 4;
    int gate = nt >> 3;
    int col = (nt & 7) * 16 + l16;
    float bias = (gate == 0) ? b_mz[col] : (gate == 2) ? b_mh[col] : 0.f;
    _Float16* op = (gate == 0) ? pre_z : (gate == 1) ? pre_r : pre_h;
    #pragma unroll
    for (int mt = 0; mt < 4; ++mt)
      #pragma unroll
      for (int r = 0; r < 4; ++r) {
        int row = mt * 16 + quad * 4 + r;
        op[((size_t)b * Tc + t0 + row) * Hc + col] = (_Float16)(accB[mt][j][r] + bias);
      }
  }
}

// ---------------------------------------------------------------------------
// K3: sequential h-recurrence, fp16-dot2 version.
// 256 threads = (col j 0..127) x (k-half). Wave = uniform k-half -> all LDS
// b128 reads are single-address broadcasts (conflict-free). z & r share each
// hd read. Both halves redundantly track h/z/hd (no serial owner phase).
// Weights: 96 packed-fp16 VGPRs per thread. 4 barriers/step.
// ---------------------------------------------------------------------------
__global__ __launch_bounds__(256, 2) void k_seq(
    const _Float16* __restrict__ gamma16, const _Float16* __restrict__ pz16,
    const _Float16* __restrict__ pr16, const _Float16* __restrict__ ph16,
    const unsigned int* __restrict__ whT, float* __restrict__ hs_out) {
  const int b = blockIdx.x;
  const int tid = threadIdx.x;
  const int j = tid & 127;
  const int half = tid >> 7;          // waves 0,1 -> half 0; waves 2,3 -> half 1

  __shared__ unsigned int hd16[64];    // packed fp16 pairs of hd
  __shared__ unsigned int rhd16[64];   // packed fp16 pairs of r*hd
  __shared__ float2 pbzr[2][128];      // z/r partials per half
  __shared__ float  phc[2][128];       // h~ partials per half

  uint4 wz[8], wr[8], wh[8];
  {
    const uint4* p0 = reinterpret_cast<const uint4*>(whT + 0 * 8192 + j * 64 + half * 32);
    const uint4* p1 = reinterpret_cast<const uint4*>(whT + 1 * 8192 + j * 64 + half * 32);
    const uint4* p2 = reinterpret_cast<const uint4*>(whT + 2 * 8192 + j * 64 + half * 32);
    #pragma unroll
    for (int i = 0; i < 8; ++i) { wz[i] = p0[i]; wr[i] = p1[i]; wh[i] = p2[i]; }
  }

  const size_t b0 = (size_t)b * Tc * Hc;
  float h_j = 0.f;
  float gv  = (float)gamma16[b0 + j];
  float pvz = (float)pz16[b0 + j];
  float pvr = (float)pr16[b0 + j];
  float pvh = (float)ph16[b0 + j];

  const uint4* hp4 = reinterpret_cast<const uint4*>(hd16) + half * 8;
  const uint4* rp4 = reinterpret_cast<const uint4*>(rhd16) + half * 8;

  for (int t = 0; t < Tc; ++t) {
    // s1: hd (both halves), half0 publishes fp16
    float hd_j = gv * h_j;
    if (half == 0) reinterpret_cast<_Float16*>(hd16)[j] = (_Float16)hd_j;
    __syncthreads();

    // prefetch t+1 streams (consumed next iteration)
    int tn = (t + 1 < Tc) ? t + 1 : t;
    size_t nb = b0 + (size_t)tn * Hc + j;
    float gv_n = (float)gamma16[nb];
    float pz_n = (float)pz16[nb];
    float pr_n = (float)pr16[nb];
    float ph_n = (float)ph16[nb];

    // s2: z & r half-dots (broadcast b128 reads, shared between gates)
    float zp = 0.f, rpp = 0.f;
    #pragma unroll
    for (int i = 0; i < 8; ++i) {
      uint4 hv = hp4[i];
      zp = dot2f(hv.x, wz[i].x, zp); rpp = dot2f(hv.x, wr[i].x, rpp);
      zp = dot2f(hv.y, wz[i].y, zp); rpp = dot2f(hv.y, wr[i].y, rpp);
      zp = dot2f(hv.z, wz[i].z, zp); rpp = dot2f(hv.z, wr[i].z, rpp);
      zp = dot2f(hv.w, wz[i].w, zp); rpp = dot2f(hv.w, wr[i].w, rpp);
    }
    pbzr[half][j] = make_float2(zp, rpp);
    __syncthreads();

    // s3: combine halves symmetrically; gates; half1 publishes r*hd fp16
    float2 opp = pbzr[half ^ 1][j];
    float z = sigf(pvz + zp + opp.x);
    float r = sigf(pvr + rpp + opp.y);
    float rhd = r * hd_j;
    if (half == 1) reinterpret_cast<_Float16*>(rhd16)[j] = (_Float16)rhd;
    __syncthreads();

    // s4: h~ half-dot
    float hpp = 0.f;
    #pragma unroll
    for (int i = 0; i < 8; ++i) {
      uint4 rv = rp4[i];
      hpp = dot2f(rv.x, wh[i].x, hpp);
      hpp = dot2f(rv.y, wh[i].y, hpp);
      hpp = dot2f(rv.z, wh[i].z, hpp);
      hpp = dot2f(rv.w, wh[i].w, hpp);
    }
    phc[half][j] = hpp;
    __syncthreads();

    // s5: combine, tanh, update (both halves identically), half0 stores
    float hsum = pvh + hpp + phc[half ^ 1][j];
    float e2 = __expf(2.f * hsum);
    float ht = 1.f - 2.f / (e2 + 1.f);   // overflow-safe tanh
    float hn = (1.f - z) * hd_j + z * ht;
    h_j = hn;
    if (half == 0) hs_out[b0 + (size_t)t * Hc + j] = hn;
    gv = gv_n; pvz = pz_n; pvr = pr_n; pvh = ph_n;
  }
}

// ---------------------------------------------------------------------------
// K4: ys = sigmoid(hs @ w_hy + b_hy) via MFMA bf16 (unchanged).
// ---------------------------------------------------------------------------
__global__ __launch_bounds__(256) void k_y(const float* __restrict__ hs,
                                           const unsigned short* __restrict__ hyT,
                                           const float* __restrict__ b_hy,
                                           float* __restrict__ ys) {
  __shared__ unsigned short A16[64 * 136];
  const int tid = threadIdx.x;
  const int r0 = blockIdx.x * 64;
  const int w = tid >> 6, lane = tid & 63, quad = lane >> 4, l16 = lane & 15;

  #pragma unroll
  for (int i = 0; i < 8; ++i) {
    int e = tid + i * 256;
    int row = e >> 5, k4 = (e & 31) * 4;
    float4 hv = *reinterpret_cast<const float4*>(&hs[(size_t)(r0 + row) * Hc + k4]);
    unsigned short s0 = f2b(hv.x), s1 = f2b(hv.y), s2 = f2b(hv.z), s3 = f2b(hv.w);
    unsigned int lo = (unsigned int)s0 | ((unsigned int)s1 << 16);
    unsigned int hi = (unsigned int)s2 | ((unsigned int)s3 << 16);
    *reinterpret_cast<uint2*>(&A16[row * 136 + k4]) = make_uint2(lo, hi);
  }
  __syncthreads();

  f32x4 acc[4];
  #pragma unroll
  for (int mt = 0; mt < 4; ++mt) acc[mt] = {0.f, 0.f, 0.f, 0.f};
  #pragma unroll
  for (int kt = 0; kt < 4; ++kt) {
    bf16x8 bb = *reinterpret_cast<const bf16x8*>(hyT + (w * 16 + l16) * 128 + kt * 32 + quad * 8);
    #pragma unroll
    for (int mt = 0; mt < 4; ++mt) {
      bf16x8 a = *reinterpret_cast<const bf16x8*>(&A16[(mt * 16 + l16) * 136 + kt * 32 + quad * 8]);
      acc[mt] = __builtin_amdgcn_mfma_f32_16x16x32_bf16(a, bb, acc[mt], 0, 0, 0);
    }
  }
  int col = w * 16 + l16;
  float bias = b_hy[col];
  #pragma unroll
  for (int mt = 0; mt < 4; ++mt)
    #pragma unroll
    for (int r = 0; r < 4; ++r) {
      int row = mt * 16 + quad * 4 + r;
      ys[(size_t)(r0 + row) * Oc + col] = 1.f / (1.f + __expf(-(acc[mt][r] + bias)));
    }
}

// ---------------------------------------------------------------------------
extern "C" void kernel_launch(void* const* d_in, const int* in_sizes, int n_in,
                              void* d_out, int out_size, void* d_ws, size_t ws_size,
                              hipStream_t stream) {
  const float* input  = (const float*)d_in[0];
  const float* x_mean = (const float*)d_in[1];
  const float* lastx  = (const float*)d_in[2];
  const float* w_dg_x = (const float*)d_in[3];
  const float* b_dg_x = (const float*)d_in[4];
  const float* w_dg_h = (const float*)d_in[5];
  const float* b_dg_h = (const float*)d_in[6];
  const float* w_xz   = (const float*)d_in[7];
  const float* w_hz   = (const float*)d_in[8];
  const float* w_mz   = (const float*)d_in[9];
  const float* b_mz   = (const float*)d_in[10];
  const float* w_xr   = (const float*)d_in[11];
  const float* w_hr   = (const float*)d_in[12];
  const float* w_mr   = (const float*)d_in[13];
  const float* w_xh   = (const float*)d_in[14];
  const float* w_hh   = (const float*)d_in[15];
  const float* w_mh   = (const float*)d_in[16];
  const float* b_mh   = (const float*)d_in[17];
  const float* w_hy   = (const float*)d_in[18];
  const float* b_hy   = (const float*)d_in[19];

  float* ys = (float*)d_out;                          // (B,T,O)
  float* hs = (float*)d_out + (size_t)Bc * Tc * Oc;   // (B,T,H)

  const size_t BTC = (size_t)Bc * Tc * Cc;            // 8,388,608
  const size_t BTH = (size_t)Bc * Tc * Hc;            // 16,777,216

  float* xlast = (float*)d_ws;
  _Float16* gamma16 = (_Float16*)(xlast + BTC);
  _Float16* pz16 = gamma16 + BTH;
  _Float16* pr16 = pz16 + BTH;
  _Float16* ph16p = pr16 + BTH;
  unsigned short* wdgT = (unsigned short*)(ph16p + BTH);   // 192*64 bf16
  unsigned short* w2T  = wdgT + 192 * 64;                  // 384*128 bf16
  unsigned short* hyT  = w2T + 384 * 128;                  // 64*128 bf16
  unsigned int*   whT  = (unsigned int*)(hyT + 64 * 128);  // 3*128*64 packed fp16

  k_wprep<<<368, 256, 0, stream>>>(w_dg_x, w_dg_h, w_xz, w_mz, w_xr, w_mr,
                                   w_xh, w_mh, w_hy, w_hz, w_hr, w_hh,
                                   wdgT, w2T, hyT, whT);
  k_scan<<<Bc, 256, 0, stream>>>(input, lastx, xlast);
  k_pre<<<(Bc * Tc) / 64, 256, 0, stream>>>(input, x_mean, xlast,
                                            b_dg_x, b_dg_h, b_mz, b_mh,
                                            wdgT, w2T,
                                            gamma16, pz16, pr16, ph16p);
  k_seq<<<Bc, 256, 0, stream>>>(gamma16, pz16, pr16, ph16p, whT, hs);
  k_y<<<(Bc * Tc) / 64, 256, 0, stream>>>(hs, hyT, b_hy, ys);
}